// Round 3
// baseline (655.626 us; speedup 1.0000x reference)
//
#include <hip/hip_runtime.h>

#define DIMM 768
#define NH 12
#define HD 64
#define LSEQ 1024
#define BATCH 4

typedef __bf16 bf16x8 __attribute__((ext_vector_type(8)));
typedef unsigned short u16x8 __attribute__((ext_vector_type(8)));
typedef float f32x4 __attribute__((ext_vector_type(4)));

static __device__ __forceinline__ unsigned short f2bf(float f) {
  unsigned u = __builtin_bit_cast(unsigned, f);
  u += 0x7fffu + ((u >> 16) & 1u);
  return (unsigned short)(u >> 16);
}
static __device__ __forceinline__ float bf2f(unsigned short h) {
  unsigned u = ((unsigned)h) << 16;
  return __builtin_bit_cast(float, u);
}
static __device__ __forceinline__ bf16x8 ld8bf(const unsigned short* p) {
  uint4 u = *(const uint4*)p;
  return __builtin_bit_cast(bf16x8, u);
}
// load 8 fp32 (two float4), split into hi/lo bf16 pair (hi+lo ~2^-17 rel)
static __device__ __forceinline__ void load_split(const float* __restrict__ p,
                                                  bf16x8& h8, bf16x8& l8) {
  float4 v0 = *(const float4*)p;
  float4 v1 = *(const float4*)(p + 4);
  float x[8] = {v0.x, v0.y, v0.z, v0.w, v1.x, v1.y, v1.z, v1.w};
  u16x8 uh, ul;
#pragma unroll
  for (int i = 0; i < 8; ++i) {
    unsigned short h = f2bf(x[i]);
    uh[i] = h;
    ul[i] = f2bf(x[i] - bf2f(h));
  }
  h8 = __builtin_bit_cast(bf16x8, uh);
  l8 = __builtin_bit_cast(bf16x8, ul);
}
static __device__ __forceinline__ bf16x8 load_rnd(const float* __restrict__ p) {
  float4 v0 = *(const float4*)p;
  float4 v1 = *(const float4*)(p + 4);
  float x[8] = {v0.x, v0.y, v0.z, v0.w, v1.x, v1.y, v1.z, v1.w};
  u16x8 uh;
#pragma unroll
  for (int i = 0; i < 8; ++i) uh[i] = f2bf(x[i]);
  return __builtin_bit_cast(bf16x8, uh);
}
#define MFMA(a, b, c) __builtin_amdgcn_mfma_f32_16x16x32_bf16(a, b, c, 0, 0, 0)

// ---------------- Kernel A: QKV projections (fp32 in) ----------------
// C[m,n] = sum_k X[m,k]*W[n,k]; M=4096 N=768 K=768.
// proj 0/1 -> q/k hi+lo bf16 [B,H,L,hd] (3-pass hi/lo MFMA, rel err ~2^-17)
// proj 2   -> v single-bf16, transposed [B,H,hd,L]
__global__ __launch_bounds__(256) void qkv_proj(
    const float* __restrict__ q_in, const float* __restrict__ k_in,
    const float* __restrict__ v_in, const float* __restrict__ Wq,
    const float* __restrict__ Wk, const float* __restrict__ Wv,
    unsigned short* __restrict__ qhi, unsigned short* __restrict__ qlo,
    unsigned short* __restrict__ khi, unsigned short* __restrict__ klo,
    unsigned short* __restrict__ vT) {
  const int proj = blockIdx.z;
  const float* X = proj == 0 ? q_in : (proj == 1 ? k_in : v_in);
  const float* W = proj == 0 ? Wq : (proj == 1 ? Wk : Wv);
  const int tid = threadIdx.x, wave = tid >> 6, lane = tid & 63;
  const int quad = lane >> 4, l15 = lane & 15;
  const int bm = blockIdx.x * 64 + (wave >> 1) * 32;
  const int bn = blockIdx.y * 64 + (wave & 1) * 32;
  f32x4 acc[2][2] = {};
  if (proj < 2) {
    for (int kk = 0; kk < DIMM; kk += 32) {
      int ko = kk + quad * 8;
      bf16x8 ah0, al0, ah1, al1, bh0, bl0, bh1, bl1;
      load_split(X + (bm + l15) * DIMM + ko, ah0, al0);
      load_split(X + (bm + 16 + l15) * DIMM + ko, ah1, al1);
      load_split(W + (bn + l15) * DIMM + ko, bh0, bl0);
      load_split(W + (bn + 16 + l15) * DIMM + ko, bh1, bl1);
      acc[0][0] = MFMA(ah0, bh0, acc[0][0]);
      acc[0][0] = MFMA(ah0, bl0, acc[0][0]);
      acc[0][0] = MFMA(al0, bh0, acc[0][0]);
      acc[0][1] = MFMA(ah0, bh1, acc[0][1]);
      acc[0][1] = MFMA(ah0, bl1, acc[0][1]);
      acc[0][1] = MFMA(al0, bh1, acc[0][1]);
      acc[1][0] = MFMA(ah1, bh0, acc[1][0]);
      acc[1][0] = MFMA(ah1, bl0, acc[1][0]);
      acc[1][0] = MFMA(al1, bh0, acc[1][0]);
      acc[1][1] = MFMA(ah1, bh1, acc[1][1]);
      acc[1][1] = MFMA(ah1, bl1, acc[1][1]);
      acc[1][1] = MFMA(al1, bh1, acc[1][1]);
    }
  } else {
    for (int kk = 0; kk < DIMM; kk += 32) {
      int ko = kk + quad * 8;
      bf16x8 a0 = load_rnd(X + (bm + l15) * DIMM + ko);
      bf16x8 a1 = load_rnd(X + (bm + 16 + l15) * DIMM + ko);
      bf16x8 b0 = load_rnd(W + (bn + l15) * DIMM + ko);
      bf16x8 b1 = load_rnd(W + (bn + 16 + l15) * DIMM + ko);
      acc[0][0] = MFMA(a0, b0, acc[0][0]);
      acc[0][1] = MFMA(a0, b1, acc[0][1]);
      acc[1][0] = MFMA(a1, b0, acc[1][0]);
      acc[1][1] = MFMA(a1, b1, acc[1][1]);
    }
  }
#pragma unroll
  for (int i = 0; i < 2; ++i)
#pragma unroll
    for (int j = 0; j < 2; ++j)
#pragma unroll
      for (int r = 0; r < 4; ++r) {
        int row = bm + i * 16 + quad * 4 + r;  // (b,l)
        int col = bn + j * 16 + l15;           // (h,d)
        float c = acc[i][j][r];
        int b = row >> 10, l = row & 1023, h = col >> 6, d = col & 63;
        if (proj < 2) {
          int idx = ((b * NH + h) * LSEQ + l) * HD + d;
          unsigned short hi = f2bf(c);
          unsigned short lo = f2bf(c - bf2f(hi));
          if (proj == 0) { qhi[idx] = hi; qlo[idx] = lo; }
          else           { khi[idx] = hi; klo[idx] = lo; }
        } else {
          vT[((b * NH + h) * HD + d) * LSEQ + l] = f2bf(c);
        }
      }
}

// ---------------- Kernel B: fused attention core ----------------
__global__ __launch_bounds__(256) void attn_core(
    const unsigned short* __restrict__ qhi, const unsigned short* __restrict__ qlo,
    const unsigned short* __restrict__ khi, const unsigned short* __restrict__ klo,
    const unsigned short* __restrict__ vT,
    const float* __restrict__ relk, const float* __restrict__ relv,
    float* __restrict__ attn_out, unsigned short* __restrict__ wbuf) {
  __shared__ __align__(16) float S[16][1028];  // +4 pad: 2-way alias only (free)
  __shared__ float qrel[16][7];
  __shared__ float arel[16][7];
  __shared__ float rvt[7][64];

  const int qt = blockIdx.x, h = blockIdx.y, b = blockIdx.z;
  const int q0 = qt * 16;
  const int tid = threadIdx.x, wave = tid >> 6, lane = tid & 63;
  const int quad = lane >> 4, l15 = lane & 15;
  const int bhd = b * NH + h;

  // phase 0: rel_v table -> LDS; qrel[q][r] = (q_hi+q_lo) . rel_k_table[r]
  for (int t = tid; t < 7 * HD; t += 256) rvt[t >> 6][t & 63] = relv[t];
  if (tid < 112) {
    int q = tid / 7, rr = tid % 7;
    const unsigned short* qp = qhi + (bhd * LSEQ + q0 + q) * HD;
    const unsigned short* lp = qlo + (bhd * LSEQ + q0 + q) * HD;
    const float* tp = relk + rr * HD;
    float s = 0.f;
    for (int d = 0; d < HD; ++d) s += (bf2f(qp[d]) + bf2f(lp[d])) * tp[d];
    qrel[q][rr] = s;
  }

  // phase 1: S = Q K^T, hi/lo 3-term split
  {
    const int qbase = (bhd * LSEQ + q0 + l15) * HD + quad * 8;
    bf16x8 ah0 = ld8bf(qhi + qbase);
    bf16x8 ah1 = ld8bf(qhi + qbase + 32);
    bf16x8 al0 = ld8bf(qlo + qbase);
    bf16x8 al1 = ld8bf(qlo + qbase + 32);
    for (int nt = wave; nt < 64; nt += 4) {
      const int krow = (bhd * LSEQ + nt * 16 + l15) * HD + quad * 8;
      bf16x8 kh0 = ld8bf(khi + krow);
      bf16x8 kh1 = ld8bf(khi + krow + 32);
      bf16x8 kl0 = ld8bf(klo + krow);
      bf16x8 kl1 = ld8bf(klo + krow + 32);
      f32x4 acc = {};
      acc = MFMA(ah0, kh0, acc);
      acc = MFMA(ah1, kh1, acc);
      acc = MFMA(ah0, kl0, acc);
      acc = MFMA(ah1, kl1, acc);
      acc = MFMA(al0, kh0, acc);
      acc = MFMA(al1, kh1, acc);
#pragma unroll
      for (int r = 0; r < 4; ++r) S[quad * 4 + r][nt * 16 + l15] = acc[r];
    }
  }
  __syncthreads();

  // phase 2: + rel scores, *8, softmax, attn write (fp32), bucket edge sums
  for (int rr = 0; rr < 4; ++rr) {
    const int qr = wave * 4 + rr;
    const int qa = q0 + qr;
    float vals[16];
    float mx = -3.4e38f;
#pragma unroll
    for (int i = 0; i < 16; ++i) {
      int c = i * 64 + lane;
      int d = c - qa;
      int ri = d < -3 ? 0 : (d > 3 ? 6 : d + 3);
      float s = (S[qr][c] + qrel[qr][ri]) * 8.0f;  // ref divides by hd^-0.5
      vals[i] = s;
      mx = fmaxf(mx, s);
    }
#pragma unroll
    for (int off = 32; off > 0; off >>= 1) mx = fmaxf(mx, __shfl_xor(mx, off));
    float sum = 0.f, s0 = 0.f, s6 = 0.f;
#pragma unroll
    for (int i = 0; i < 16; ++i) {
      int c = i * 64 + lane;
      float e = __expf(vals[i] - mx);
      vals[i] = e;
      sum += e;
      if (c <= qa - 3) s0 += e;
      if (c >= qa + 3) s6 += e;
    }
#pragma unroll
    for (int off = 32; off > 0; off >>= 1) {
      sum += __shfl_xor(sum, off);
      s0 += __shfl_xor(s0, off);
      s6 += __shfl_xor(s6, off);
    }
    float rn = 1.0f / sum;
    float* ao = attn_out + ((size_t)(bhd * LSEQ + qa)) * LSEQ;
#pragma unroll
    for (int i = 0; i < 16; ++i) {
      int c = i * 64 + lane;
      float p = vals[i] * rn;
      S[qr][c] = p;
      ao[c] = p;
    }
    if (lane == 0) { arel[qr][0] = s0 * rn; arel[qr][6] = s6 * rn; }
  }
  __syncthreads();
  // singleton buckets r=1..5: attn[q, q+r-3]
  if (tid < 80) {
    int qr = tid / 5, m = tid % 5;
    int kidx = q0 + qr + m - 2;
    arel[qr][m + 1] = (kidx >= 0 && kidx < LSEQ) ? S[qr][kidx] : 0.f;
  }
  __syncthreads();

  // phase 3: W1 = P @ V (wave -> 16 d-cols) + W2 = arel @ rel_v
  {
    const unsigned short* vb = vT + (bhd * HD + wave * 16 + l15) * LSEQ;
    f32x4 acc = {};
    for (int kk = 0; kk < LSEQ; kk += 32) {
      int ak = kk + quad * 8;
      float4 p0 = *(const float4*)&S[l15][ak];
      float4 p1 = *(const float4*)&S[l15][ak + 4];
      u16x8 up;
      up[0] = f2bf(p0.x); up[1] = f2bf(p0.y); up[2] = f2bf(p0.z); up[3] = f2bf(p0.w);
      up[4] = f2bf(p1.x); up[5] = f2bf(p1.y); up[6] = f2bf(p1.z); up[7] = f2bf(p1.w);
      bf16x8 aP = __builtin_bit_cast(bf16x8, up);
      bf16x8 bV = ld8bf(vb + ak);
      acc = MFMA(aP, bV, acc);
    }
    const int col = wave * 16 + l15;  // d
#pragma unroll
    for (int r = 0; r < 4; ++r) {
      int row = quad * 4 + r;  // q within tile
      float w2 = 0.f;
#pragma unroll
      for (int t = 0; t < 7; ++t) w2 += arel[row][t] * rvt[t][col];
      wbuf[(b * LSEQ + q0 + row) * DIMM + h * HD + col] = f2bf(acc[r] + w2);
    }
  }
}

// ---------------- Kernel C: output projection + bias (fp32 out) ----------------
__global__ __launch_bounds__(256) void out_proj(
    const unsigned short* __restrict__ wbuf, const float* __restrict__ Wp,
    const float* __restrict__ bias, float* __restrict__ out) {
  const int tid = threadIdx.x, wave = tid >> 6, lane = tid & 63;
  const int quad = lane >> 4, l15 = lane & 15;
  const int bm = blockIdx.x * 64 + (wave >> 1) * 32;
  const int bn = blockIdx.y * 64 + (wave & 1) * 32;
  f32x4 acc[2][2] = {};
  for (int kk = 0; kk < DIMM; kk += 32) {
    int ko = kk + quad * 8;
    bf16x8 a0 = ld8bf(wbuf + (bm + l15) * DIMM + ko);
    bf16x8 a1 = ld8bf(wbuf + (bm + 16 + l15) * DIMM + ko);
    bf16x8 b0 = load_rnd(Wp + (bn + l15) * DIMM + ko);
    bf16x8 b1 = load_rnd(Wp + (bn + 16 + l15) * DIMM + ko);
    acc[0][0] = MFMA(a0, b0, acc[0][0]);
    acc[0][1] = MFMA(a0, b1, acc[0][1]);
    acc[1][0] = MFMA(a1, b0, acc[1][0]);
    acc[1][1] = MFMA(a1, b1, acc[1][1]);
  }
#pragma unroll
  for (int i = 0; i < 2; ++i)
#pragma unroll
    for (int j = 0; j < 2; ++j)
#pragma unroll
      for (int r = 0; r < 4; ++r) {
        int row = bm + i * 16 + quad * 4 + r;
        int col = bn + j * 16 + l15;
        out[row * DIMM + col] = acc[i][j][r] + bias[col];
      }
}

extern "C" void kernel_launch(void* const* d_in, const int* in_sizes, int n_in,
                              void* d_out, int out_size, void* d_ws, size_t ws_size,
                              hipStream_t stream) {
  const float* q_in = (const float*)d_in[0];
  const float* k_in = (const float*)d_in[1];
  const float* v_in = (const float*)d_in[2];
  const float* Wq   = (const float*)d_in[3];
  const float* Wk   = (const float*)d_in[4];
  const float* Wv   = (const float*)d_in[5];
  const float* Wp   = (const float*)d_in[6];
  const float* bias = (const float*)d_in[7];
  const float* relk = (const float*)d_in[8];
  const float* relv = (const float*)d_in[9];
  float* out = (float*)d_out;

  const size_t NE = (size_t)BATCH * NH * LSEQ * HD;  // 3,145,728 == B*L*DIM
  unsigned short* qhi  = (unsigned short*)d_ws;
  unsigned short* qlo  = qhi + NE;
  unsigned short* khi  = qlo + NE;
  unsigned short* klo  = khi + NE;
  unsigned short* vT   = klo + NE;
  unsigned short* wbuf = vT + NE;

  qkv_proj<<<dim3(64, 12, 3), 256, 0, stream>>>(q_in, k_in, v_in, Wq, Wk, Wv,
                                                qhi, qlo, khi, klo, vT);
  attn_core<<<dim3(64, NH, BATCH), 256, 0, stream>>>(qhi, qlo, khi, klo, vT,
                                                     relk, relv, out + NE, wbuf);
  out_proj<<<dim3(64, 12, 1), 256, 0, stream>>>(wbuf, Wp, bias, out);
}

// Round 5
// 487.878 us; speedup vs baseline: 1.3438x; 1.3438x over previous
//
#include <hip/hip_runtime.h>

#define DIMM 768
#define NH 12
#define HD 64
#define LSEQ 1024
#define BATCH 4
#define NXE 3145728   // 4096*768
#define NWE 589824    // 768*768

typedef __bf16 bf16x8 __attribute__((ext_vector_type(8)));
typedef float f32x4 __attribute__((ext_vector_type(4)));
typedef unsigned short u16;
typedef unsigned short u16x8 __attribute__((ext_vector_type(8)));

static __device__ __forceinline__ u16 f2bf(float f) {
  unsigned u = __builtin_bit_cast(unsigned, f);
  u += 0x7fffu + ((u >> 16) & 1u);
  return (u16)(u >> 16);
}
static __device__ __forceinline__ float bf2f(u16 h) {
  unsigned u = ((unsigned)h) << 16;
  return __builtin_bit_cast(float, u);
}
static __device__ __forceinline__ bf16x8 ld8bf(const u16* p) {
  uint4 u = *(const uint4*)p;
  return __builtin_bit_cast(bf16x8, u);
}
#define MFMA(a, b, c) __builtin_amdgcn_mfma_f32_16x16x32_bf16(a, b, c, 0, 0, 0)
#define GLL(g, s)                                                      \
  __builtin_amdgcn_global_load_lds(                                    \
      (const __attribute__((address_space(1))) void*)(g),              \
      (__attribute__((address_space(3))) void*)(s), 16, 0, 0)

// ---------- Kernel 0: fp32 -> bf16 hi/lo conversion prepass ----------
__global__ __launch_bounds__(256) void convert(
    const float* __restrict__ q_in, const float* __restrict__ k_in,
    const float* __restrict__ v_in, const float* __restrict__ Wq,
    const float* __restrict__ Wk, const float* __restrict__ Wv,
    const float* __restrict__ Wp, u16* __restrict__ AqH, u16* __restrict__ AqL,
    u16* __restrict__ AkH, u16* __restrict__ AkL, u16* __restrict__ Av,
    u16* __restrict__ WqH, u16* __restrict__ WqL, u16* __restrict__ WkH,
    u16* __restrict__ WkL, u16* __restrict__ Wvr, u16* __restrict__ Wpr) {
  long i = ((long)blockIdx.x * 256 + threadIdx.x) * 4;
  const float* src;
  u16 *dh, *dl = nullptr;
  long off;
  if (i < NXE) { src = q_in; dh = AqH; dl = AqL; off = i; }
  else if (i < 2L * NXE) { src = k_in; dh = AkH; dl = AkL; off = i - NXE; }
  else if (i < 3L * NXE) { src = v_in; dh = Av; off = i - 2L * NXE; }
  else {
    long j = i - 3L * NXE;
    int which = (int)(j / NWE);
    off = j % NWE;
    if (which == 0) { src = Wq; dh = WqH; dl = WqL; }
    else if (which == 1) { src = Wk; dh = WkH; dl = WkL; }
    else if (which == 2) { src = Wv; dh = Wvr; }
    else { src = Wp; dh = Wpr; }
  }
  float4 v = *(const float4*)(src + off);
  ushort4 h;
  h.x = f2bf(v.x); h.y = f2bf(v.y); h.z = f2bf(v.z); h.w = f2bf(v.w);
  *(ushort4*)(dh + off) = h;
  if (dl) {
    ushort4 lo;
    lo.x = f2bf(v.x - bf2f(h.x)); lo.y = f2bf(v.y - bf2f(h.y));
    lo.z = f2bf(v.z - bf2f(h.z)); lo.w = f2bf(v.w - bf2f(h.w));
    *(ushort4*)(dl + off) = lo;
  }
}

// ---------- Kernel 1/3: LDS-staged MFMA GEMM, C[m,n]=sum_k A[m,k]B[n,k] ----------
// tile 64x128, BK=32; mode = mode0+z: 0=Qproj(split) 1=Kproj(split)
// 2=Vproj(plain,transposed out) 3=outproj(plain, +bias, fp32 out)
__global__ __launch_bounds__(256) void gemm_multi(
    int mode0, const u16* __restrict__ AqH, const u16* __restrict__ AqL,
    const u16* __restrict__ AkH, const u16* __restrict__ AkL,
    const u16* __restrict__ Av, const u16* __restrict__ WqH,
    const u16* __restrict__ WqL, const u16* __restrict__ WkH,
    const u16* __restrict__ WkL, const u16* __restrict__ Wvr,
    const u16* __restrict__ Wpr, const u16* __restrict__ wbuf,
    u16* __restrict__ qhi, u16* __restrict__ qlo, u16* __restrict__ khi,
    u16* __restrict__ klo, u16* __restrict__ vT, float* __restrict__ outp,
    const float* __restrict__ bias) {
  __shared__ u16 sAh[64 * 32], sAl[64 * 32];
  __shared__ u16 sBh[128 * 32], sBl[128 * 32];
  const int mode = mode0 + blockIdx.z;
  const u16 *Ah, *Al = nullptr, *Bh, *Bl = nullptr;
  if (mode == 0) { Ah = AqH; Al = AqL; Bh = WqH; Bl = WqL; }
  else if (mode == 1) { Ah = AkH; Al = AkL; Bh = WkH; Bl = WkL; }
  else if (mode == 2) { Ah = Av; Bh = Wvr; }
  else { Ah = wbuf; Bh = Wpr; }
  const int t = threadIdx.x, w = t >> 6, l = t & 63;
  const int quad = l >> 4, l15 = l & 15;
  const int m0 = blockIdx.x * 64, n0 = blockIdx.y * 128;
  const int wm = (w >> 1) * 32, wn = (w & 1) * 64;
  const int srow = t >> 2, scol = (t & 3) * 8;
  const u16* gA = Ah + (m0 + srow) * DIMM + scol;
  const u16* gB = Bh + (n0 + srow) * DIMM + scol;
  u16* lA = sAh + w * 512;
  u16* lB = sBh + w * 512;
  f32x4 acc[2][4] = {};
  if (mode < 2) {
    const u16* gAl = Al + (m0 + srow) * DIMM + scol;
    const u16* gBl = Bl + (n0 + srow) * DIMM + scol;
    u16* lAl = sAl + w * 512;
    u16* lBl = sBl + w * 512;
    for (int k0 = 0; k0 < DIMM; k0 += 32) {
      GLL(gA + k0, lA);
      GLL(gAl + k0, lAl);
      GLL(gB + k0, lB);
      GLL(gB + 64 * DIMM + k0, lB + 2048);
      GLL(gBl + k0, lBl);
      GLL(gBl + 64 * DIMM + k0, lBl + 2048);
      __syncthreads();
      bf16x8 ah[2], aL[2], bh[4], bL[4];
#pragma unroll
      for (int i = 0; i < 2; ++i) {
        int r = (wm + i * 16 + l15) * 32 + quad * 8;
        ah[i] = __builtin_bit_cast(bf16x8, *(const uint4*)(sAh + r));
        aL[i] = __builtin_bit_cast(bf16x8, *(const uint4*)(sAl + r));
      }
#pragma unroll
      for (int j = 0; j < 4; ++j) {
        int r = (wn + j * 16 + l15) * 32 + quad * 8;
        bh[j] = __builtin_bit_cast(bf16x8, *(const uint4*)(sBh + r));
        bL[j] = __builtin_bit_cast(bf16x8, *(const uint4*)(sBl + r));
      }
#pragma unroll
      for (int i = 0; i < 2; ++i)
#pragma unroll
        for (int j = 0; j < 4; ++j) {
          acc[i][j] = MFMA(ah[i], bh[j], acc[i][j]);
          acc[i][j] = MFMA(ah[i], bL[j], acc[i][j]);
          acc[i][j] = MFMA(aL[i], bh[j], acc[i][j]);
        }
      __syncthreads();
    }
  } else {
    for (int k0 = 0; k0 < DIMM; k0 += 32) {
      GLL(gA + k0, lA);
      GLL(gB + k0, lB);
      GLL(gB + 64 * DIMM + k0, lB + 2048);
      __syncthreads();
      bf16x8 ah[2], bh[4];
#pragma unroll
      for (int i = 0; i < 2; ++i)
        ah[i] = __builtin_bit_cast(
            bf16x8, *(const uint4*)(sAh + (wm + i * 16 + l15) * 32 + quad * 8));
#pragma unroll
      for (int j = 0; j < 4; ++j)
        bh[j] = __builtin_bit_cast(
            bf16x8, *(const uint4*)(sBh + (wn + j * 16 + l15) * 32 + quad * 8));
#pragma unroll
      for (int i = 0; i < 2; ++i)
#pragma unroll
        for (int j = 0; j < 4; ++j) acc[i][j] = MFMA(ah[i], bh[j], acc[i][j]);
      __syncthreads();
    }
  }
  // epilogue
  u16* oh = (mode == 0) ? qhi : khi;
  u16* ol = (mode == 0) ? qlo : klo;
#pragma unroll
  for (int i = 0; i < 2; ++i)
#pragma unroll
    for (int j = 0; j < 4; ++j)
#pragma unroll
      for (int r = 0; r < 4; ++r) {
        int grow = m0 + wm + i * 16 + quad * 4 + r;  // (b,l)
        int gcol = n0 + wn + j * 16 + l15;           // (h,d)
        float c = acc[i][j][r];
        int b = grow >> 10, ll = grow & 1023, h = gcol >> 6, d = gcol & 63;
        if (mode < 2) {
          int idx = ((b * NH + h) * LSEQ + ll) * HD + d;
          u16 hi = f2bf(c);
          oh[idx] = hi;
          ol[idx] = f2bf(c - bf2f(hi));
        } else if (mode == 2) {
          vT[((b * NH + h) * HD + d) * LSEQ + ll] = f2bf(c);
        } else {
          outp[grow * DIMM + gcol] = c + bias[gcol];
        }
      }
}

// ---------- Kernel 2: fused attention core (fp32 S tile — precision-critical) ----------
__global__ __launch_bounds__(256) void attn_core(
    const u16* __restrict__ qhi, const u16* __restrict__ qlo,
    const u16* __restrict__ khi, const u16* __restrict__ klo,
    const u16* __restrict__ vT, const float* __restrict__ relk,
    const float* __restrict__ relv, float* __restrict__ attn_out,
    u16* __restrict__ wbuf) {
  __shared__ __align__(16) float S[16][1028];  // fp32: pre-softmax precision
  __shared__ float qrel[16][7];
  __shared__ float arel[16][7];
  __shared__ float rvt[7][64];

  const int qt = blockIdx.x, h = blockIdx.y, b = blockIdx.z;
  const int q0 = qt * 16;
  const int tid = threadIdx.x, wave = tid >> 6, lane = tid & 63;
  const int quad = lane >> 4, l15 = lane & 15;
  const int bhd = b * NH + h;

  // phase 0: rel_v -> LDS; qrel[q][r] = (q_hi+q_lo) . rel_k[r]
  for (int t = tid; t < 7 * HD; t += 256) rvt[t >> 6][t & 63] = relv[t];
  if (tid < 112) {
    int q = tid / 7, rr = tid % 7;
    const u16* qp = qhi + (bhd * LSEQ + q0 + q) * HD;
    const u16* lp = qlo + (bhd * LSEQ + q0 + q) * HD;
    const float* tp = relk + rr * HD;
    float s = 0.f;
    for (int d = 0; d < HD; ++d) s += (bf2f(qp[d]) + bf2f(lp[d])) * tp[d];
    qrel[q][rr] = s;
  }

  // phase 1: S = Q K^T (hi/lo 3-term), depth-1 register prefetch of K frags
  {
    const int qbase = (bhd * LSEQ + q0 + l15) * HD + quad * 8;
    bf16x8 ah0 = ld8bf(qhi + qbase);
    bf16x8 ah1 = ld8bf(qhi + qbase + 32);
    bf16x8 al0 = ld8bf(qlo + qbase);
    bf16x8 al1 = ld8bf(qlo + qbase + 32);
    const u16* bh = khi + (bhd * LSEQ + wave * 16 + l15) * HD + quad * 8;
    const u16* bl = klo + (bhd * LSEQ + wave * 16 + l15) * HD + quad * 8;
    bf16x8 kh0 = ld8bf(bh), kh1 = ld8bf(bh + 32);
    bf16x8 kl0 = ld8bf(bl), kl1 = ld8bf(bl + 32);
    for (int it = 0; it < 16; ++it) {
      bf16x8 nh0 = kh0, nh1 = kh1, nl0 = kl0, nl1 = kl1;
      if (it < 15) {
        const u16* ph = bh + (it + 1) * 4096;  // 4 tiles * 16 rows * 64 hd
        const u16* pl = bl + (it + 1) * 4096;
        nh0 = ld8bf(ph); nh1 = ld8bf(ph + 32);
        nl0 = ld8bf(pl); nl1 = ld8bf(pl + 32);
      }
      f32x4 acc = {};
      acc = MFMA(ah0, kh0, acc);
      acc = MFMA(ah1, kh1, acc);
      acc = MFMA(ah0, kl0, acc);
      acc = MFMA(ah1, kl1, acc);
      acc = MFMA(al0, kh0, acc);
      acc = MFMA(al1, kh1, acc);
      const int nt = wave + it * 4;
#pragma unroll
      for (int r = 0; r < 4; ++r) S[quad * 4 + r][nt * 16 + l15] = acc[r];
      kh0 = nh0; kh1 = nh1; kl0 = nl0; kl1 = nl1;
    }
  }
  __syncthreads();

  // phase 2: +rel, *8, softmax, fp32 attn write, edge buckets
  for (int rr = 0; rr < 4; ++rr) {
    const int qr = wave * 4 + rr;
    const int qa = q0 + qr;
    float vals[16];
    float mx = -3.4e38f;
#pragma unroll
    for (int i = 0; i < 16; ++i) {
      int c = i * 64 + lane;
      int d = c - qa;
      int ri = d < -3 ? 0 : (d > 3 ? 6 : d + 3);
      float s = (S[qr][c] + qrel[qr][ri]) * 8.0f;  // ref divides by hd^-0.5
      vals[i] = s;
      mx = fmaxf(mx, s);
    }
#pragma unroll
    for (int off = 32; off > 0; off >>= 1) mx = fmaxf(mx, __shfl_xor(mx, off));
    float sum = 0.f, s0 = 0.f, s6 = 0.f;
#pragma unroll
    for (int i = 0; i < 16; ++i) {
      int c = i * 64 + lane;
      float e = __expf(vals[i] - mx);
      vals[i] = e;
      sum += e;
      if (c <= qa - 3) s0 += e;
      if (c >= qa + 3) s6 += e;
    }
#pragma unroll
    for (int off = 32; off > 0; off >>= 1) {
      sum += __shfl_xor(sum, off);
      s0 += __shfl_xor(s0, off);
      s6 += __shfl_xor(s6, off);
    }
    float rn = 1.0f / sum;
    float* ao = attn_out + ((size_t)(bhd * LSEQ + qa)) * LSEQ;
#pragma unroll
    for (int i = 0; i < 16; ++i) {
      int c = i * 64 + lane;
      float p = vals[i] * rn;
      S[qr][c] = p;
      ao[c] = p;
    }
    if (lane == 0) { arel[qr][0] = s0 * rn; arel[qr][6] = s6 * rn; }
  }
  __syncthreads();
  if (tid < 80) {  // singleton buckets r=1..5: attn[q, q+r-3]
    int qr = tid / 5, m = tid % 5;
    int kidx = q0 + qr + m - 2;
    arel[qr][m + 1] = (kidx >= 0 && kidx < LSEQ) ? S[qr][kidx] : 0.f;
  }
  __syncthreads();

  // phase 3: W1 = P @ V (wave -> 16 d-cols) + W2 = arel @ rel_v
  {
    const u16* vb = vT + (bhd * HD + wave * 16 + l15) * LSEQ;
    f32x4 acc = {};
    for (int kk = 0; kk < LSEQ; kk += 32) {
      int ak = kk + quad * 8;
      float4 p0 = *(const float4*)&S[l15][ak];
      float4 p1 = *(const float4*)&S[l15][ak + 4];
      u16x8 up;
      up[0] = f2bf(p0.x); up[1] = f2bf(p0.y); up[2] = f2bf(p0.z); up[3] = f2bf(p0.w);
      up[4] = f2bf(p1.x); up[5] = f2bf(p1.y); up[6] = f2bf(p1.z); up[7] = f2bf(p1.w);
      bf16x8 aP = __builtin_bit_cast(bf16x8, up);
      bf16x8 bV = ld8bf(vb + ak);
      acc = MFMA(aP, bV, acc);
    }
    const int col = wave * 16 + l15;  // d
#pragma unroll
    for (int r = 0; r < 4; ++r) {
      int row = quad * 4 + r;  // q within tile
      float w2 = 0.f;
#pragma unroll
      for (int t = 0; t < 7; ++t) w2 += arel[row][t] * rvt[t][col];
      wbuf[(b * LSEQ + q0 + row) * DIMM + h * HD + col] = f2bf(acc[r] + w2);
    }
  }
}

extern "C" void kernel_launch(void* const* d_in, const int* in_sizes, int n_in,
                              void* d_out, int out_size, void* d_ws, size_t ws_size,
                              hipStream_t stream) {
  const float* q_in = (const float*)d_in[0];
  const float* k_in = (const float*)d_in[1];
  const float* v_in = (const float*)d_in[2];
  const float* Wq = (const float*)d_in[3];
  const float* Wk = (const float*)d_in[4];
  const float* Wv = (const float*)d_in[5];
  const float* Wp = (const float*)d_in[6];
  const float* bias = (const float*)d_in[7];
  const float* relk = (const float*)d_in[8];
  const float* relv = (const float*)d_in[9];
  float* out = (float*)d_out;

  u16* p = (u16*)d_ws;
  u16 *AqH = p, *AqL = AqH + NXE, *AkH = AqL + NXE, *AkL = AkH + NXE,
      *Av = AkL + NXE;
  u16 *WqH = Av + NXE, *WqL = WqH + NWE, *WkH = WqL + NWE, *WkL = WkH + NWE,
      *Wvr = WkL + NWE, *Wpr = Wvr + NWE;
  u16 *qhi = Wpr + NWE, *qlo = qhi + NXE, *khi = qlo + NXE, *klo = khi + NXE,
      *vT = klo + NXE, *wbuf = vT + NXE;

  convert<<<(3 * NXE + 4 * NWE) / 1024, 256, 0, stream>>>(
      q_in, k_in, v_in, Wq, Wk, Wv, Wp, AqH, AqL, AkH, AkL, Av, WqH, WqL, WkH,
      WkL, Wvr, Wpr);
  gemm_multi<<<dim3(64, 6, 3), 256, 0, stream>>>(
      0, AqH, AqL, AkH, AkL, Av, WqH, WqL, WkH, WkL, Wvr, Wpr, wbuf, qhi, qlo,
      khi, klo, vT, out, bias);
  attn_core<<<dim3(64, NH, BATCH), 256, 0, stream>>>(
      qhi, qlo, khi, klo, vT, relk, relv, out + NXE, wbuf);
  gemm_multi<<<dim3(64, 6, 1), 256, 0, stream>>>(
      3, AqH, AqL, AkH, AkL, Av, WqH, WqL, WkH, WkL, Wvr, Wpr, wbuf, qhi, qlo,
      khi, klo, vT, out, bias);
}

// Round 6
// 467.444 us; speedup vs baseline: 1.4026x; 1.0437x over previous
//
#include <hip/hip_runtime.h>

#define DIMM 768
#define NH 12
#define HD 64
#define LSEQ 1024
#define BATCH 4
#define NXE 3145728   // 4096*768
#define NWE 589824    // 768*768

typedef __bf16 bf16x8 __attribute__((ext_vector_type(8)));
typedef float f32x4 __attribute__((ext_vector_type(4)));
typedef unsigned short u16;

static __device__ __forceinline__ u16 f2bf(float f) {
  unsigned u = __builtin_bit_cast(unsigned, f);
  u += 0x7fffu + ((u >> 16) & 1u);
  return (u16)(u >> 16);
}
static __device__ __forceinline__ float bf2f(u16 h) {
  unsigned u = ((unsigned)h) << 16;
  return __builtin_bit_cast(float, u);
}
static __device__ __forceinline__ bf16x8 ld8bf(const u16* p) {
  uint4 u = *(const uint4*)p;
  return __builtin_bit_cast(bf16x8, u);
}
#define MFMA(a, b, c) __builtin_amdgcn_mfma_f32_16x16x32_bf16(a, b, c, 0, 0, 0)
#define GLL(g, s)                                                      \
  __builtin_amdgcn_global_load_lds(                                    \
      (const __attribute__((address_space(1))) void*)(g),              \
      (__attribute__((address_space(3))) void*)(s), 16, 0, 0)

// ---------- Kernel 0: fp32 -> bf16 hi/lo conversion prepass ----------
__global__ __launch_bounds__(256) void convert(
    const float* __restrict__ q_in, const float* __restrict__ k_in,
    const float* __restrict__ v_in, const float* __restrict__ Wq,
    const float* __restrict__ Wk, const float* __restrict__ Wv,
    const float* __restrict__ Wp, u16* __restrict__ AqH, u16* __restrict__ AqL,
    u16* __restrict__ AkH, u16* __restrict__ AkL, u16* __restrict__ Av,
    u16* __restrict__ WqH, u16* __restrict__ WqL, u16* __restrict__ WkH,
    u16* __restrict__ WkL, u16* __restrict__ Wvr, u16* __restrict__ Wpr) {
  long i = ((long)blockIdx.x * 256 + threadIdx.x) * 4;
  const float* src;
  u16 *dh, *dl = nullptr;
  long off;
  if (i < NXE) { src = q_in; dh = AqH; dl = AqL; off = i; }
  else if (i < 2L * NXE) { src = k_in; dh = AkH; dl = AkL; off = i - NXE; }
  else if (i < 3L * NXE) { src = v_in; dh = Av; off = i - 2L * NXE; }
  else {
    long j = i - 3L * NXE;
    int which = (int)(j / NWE);
    off = j % NWE;
    if (which == 0) { src = Wq; dh = WqH; dl = WqL; }
    else if (which == 1) { src = Wk; dh = WkH; dl = WkL; }
    else if (which == 2) { src = Wv; dh = Wvr; }
    else { src = Wp; dh = Wpr; }
  }
  float4 v = *(const float4*)(src + off);
  ushort4 h;
  h.x = f2bf(v.x); h.y = f2bf(v.y); h.z = f2bf(v.z); h.w = f2bf(v.w);
  *(ushort4*)(dh + off) = h;
  if (dl) {
    ushort4 lo;
    lo.x = f2bf(v.x - bf2f(h.x)); lo.y = f2bf(v.y - bf2f(h.y));
    lo.z = f2bf(v.z - bf2f(h.z)); lo.w = f2bf(v.w - bf2f(h.w));
    *(ushort4*)(dl + off) = lo;
  }
}

// ---------- Kernel 1/3: 128x128-tile LDS-staged MFMA GEMM ----------
// C[m,n]=sum_k A[m,k]B[n,k]; BK=32. mode: 0=Q(split) 1=K(split)
// 2=V(plain, transposed out) 3=outproj(plain, +bias, fp32 out)
__global__ __launch_bounds__(256, 3) void gemm_multi(
    int mode0, const u16* __restrict__ AqH, const u16* __restrict__ AqL,
    const u16* __restrict__ AkH, const u16* __restrict__ AkL,
    const u16* __restrict__ Av, const u16* __restrict__ WqH,
    const u16* __restrict__ WqL, const u16* __restrict__ WkH,
    const u16* __restrict__ WkL, const u16* __restrict__ Wvr,
    const u16* __restrict__ Wpr, const u16* __restrict__ wbuf,
    u16* __restrict__ qhi, u16* __restrict__ qlo, u16* __restrict__ khi,
    u16* __restrict__ klo, u16* __restrict__ vT, float* __restrict__ outp,
    const float* __restrict__ bias) {
  __shared__ u16 sAh[128 * 32], sAl[128 * 32];
  __shared__ u16 sBh[128 * 32], sBl[128 * 32];
  const int mode = mode0 + blockIdx.z;
  const u16 *Ah, *Al = nullptr, *Bh, *Bl = nullptr;
  if (mode == 0) { Ah = AqH; Al = AqL; Bh = WqH; Bl = WqL; }
  else if (mode == 1) { Ah = AkH; Al = AkL; Bh = WkH; Bl = WkL; }
  else if (mode == 2) { Ah = Av; Bh = Wvr; }
  else { Ah = wbuf; Bh = Wpr; }
  const int t = threadIdx.x, w = t >> 6, l = t & 63;
  const int quad = l >> 4, l15 = l & 15;
  const int m0 = blockIdx.x * 128, n0 = blockIdx.y * 128;
  const int wm = (w >> 1) * 64, wn = (w & 1) * 64;
  const int srow = t >> 2, scol = (t & 3) * 8;
  const u16* gA = Ah + (m0 + srow) * DIMM + scol;
  const u16* gB = Bh + (n0 + srow) * DIMM + scol;
  u16* lA = sAh + w * 512;
  u16* lB = sBh + w * 512;
  f32x4 acc[4][4] = {};
  if (mode < 2) {
    const u16* gAl = Al + (m0 + srow) * DIMM + scol;
    const u16* gBl = Bl + (n0 + srow) * DIMM + scol;
    u16* lAl = sAl + w * 512;
    u16* lBl = sBl + w * 512;
    for (int k0 = 0; k0 < DIMM; k0 += 32) {
      GLL(gA + k0, lA);
      GLL(gA + 64 * DIMM + k0, lA + 2048);
      GLL(gAl + k0, lAl);
      GLL(gAl + 64 * DIMM + k0, lAl + 2048);
      GLL(gB + k0, lB);
      GLL(gB + 64 * DIMM + k0, lB + 2048);
      GLL(gBl + k0, lBl);
      GLL(gBl + 64 * DIMM + k0, lBl + 2048);
      __syncthreads();
      bf16x8 ah[4], bh[4], xl[4];
#pragma unroll
      for (int i = 0; i < 4; ++i)
        ah[i] = __builtin_bit_cast(
            bf16x8, *(const uint4*)(sAh + (wm + i * 16 + l15) * 32 + quad * 8));
#pragma unroll
      for (int j = 0; j < 4; ++j)
        bh[j] = __builtin_bit_cast(
            bf16x8, *(const uint4*)(sBh + (wn + j * 16 + l15) * 32 + quad * 8));
#pragma unroll
      for (int i = 0; i < 4; ++i)
#pragma unroll
        for (int j = 0; j < 4; ++j) acc[i][j] = MFMA(ah[i], bh[j], acc[i][j]);
#pragma unroll
      for (int i = 0; i < 4; ++i)
        xl[i] = __builtin_bit_cast(
            bf16x8, *(const uint4*)(sAl + (wm + i * 16 + l15) * 32 + quad * 8));
#pragma unroll
      for (int i = 0; i < 4; ++i)
#pragma unroll
        for (int j = 0; j < 4; ++j) acc[i][j] = MFMA(xl[i], bh[j], acc[i][j]);
#pragma unroll
      for (int j = 0; j < 4; ++j)
        xl[j] = __builtin_bit_cast(
            bf16x8, *(const uint4*)(sBl + (wn + j * 16 + l15) * 32 + quad * 8));
#pragma unroll
      for (int i = 0; i < 4; ++i)
#pragma unroll
        for (int j = 0; j < 4; ++j) acc[i][j] = MFMA(ah[i], xl[j], acc[i][j]);
      __syncthreads();
    }
  } else {
    for (int k0 = 0; k0 < DIMM; k0 += 32) {
      GLL(gA + k0, lA);
      GLL(gA + 64 * DIMM + k0, lA + 2048);
      GLL(gB + k0, lB);
      GLL(gB + 64 * DIMM + k0, lB + 2048);
      __syncthreads();
      bf16x8 ah[4], bh[4];
#pragma unroll
      for (int i = 0; i < 4; ++i)
        ah[i] = __builtin_bit_cast(
            bf16x8, *(const uint4*)(sAh + (wm + i * 16 + l15) * 32 + quad * 8));
#pragma unroll
      for (int j = 0; j < 4; ++j)
        bh[j] = __builtin_bit_cast(
            bf16x8, *(const uint4*)(sBh + (wn + j * 16 + l15) * 32 + quad * 8));
#pragma unroll
      for (int i = 0; i < 4; ++i)
#pragma unroll
        for (int j = 0; j < 4; ++j) acc[i][j] = MFMA(ah[i], bh[j], acc[i][j]);
      __syncthreads();
    }
  }
  u16* oh = (mode == 0) ? qhi : khi;
  u16* ol = (mode == 0) ? qlo : klo;
#pragma unroll
  for (int i = 0; i < 4; ++i)
#pragma unroll
    for (int j = 0; j < 4; ++j)
#pragma unroll
      for (int r = 0; r < 4; ++r) {
        int grow = m0 + wm + i * 16 + quad * 4 + r;  // (b,l)
        int gcol = n0 + wn + j * 16 + l15;           // (h,d)
        float c = acc[i][j][r];
        int b = grow >> 10, ll = grow & 1023, h = gcol >> 6, d = gcol & 63;
        if (mode < 2) {
          int idx = ((b * NH + h) * LSEQ + ll) * HD + d;
          u16 hi = f2bf(c);
          oh[idx] = hi;
          ol[idx] = f2bf(c - bf2f(hi));
        } else if (mode == 2) {
          vT[((b * NH + h) * HD + d) * LSEQ + ll] = f2bf(c);
        } else {
          outp[grow * DIMM + gcol] = c + bias[gcol];
        }
      }
}

// ---------- Kernel 2: fused attention core, register-resident S ----------
__global__ __launch_bounds__(256, 3) void attn_core(
    const u16* __restrict__ qhi, const u16* __restrict__ qlo,
    const u16* __restrict__ khi, const u16* __restrict__ klo,
    const u16* __restrict__ vT, const float* __restrict__ relk,
    const float* __restrict__ relv, float* __restrict__ attn_out,
    u16* __restrict__ wbuf) {
  __shared__ __align__(16) u16 Pb[16][1032];  // post-softmax P (bf16), 33 KB
  __shared__ float qrel[16][7];
  __shared__ float arel[16][7];
  __shared__ float rvt[7][64];
  __shared__ float red[4][16][4];  // 0=max 1=sum 2=s0 3=s6, per-wave partials

  const int qt = blockIdx.x, h = blockIdx.y, b = blockIdx.z;
  const int q0 = qt * 16;
  const int tid = threadIdx.x, wave = tid >> 6, lane = tid & 63;
  const int quad = lane >> 4, l15 = lane & 15;
  const int bhd = b * NH + h;

  // phase 0: rel_v -> LDS; qrel; zero arel
  for (int t = tid; t < 7 * HD; t += 256) rvt[t >> 6][t & 63] = relv[t];
  if (tid < 112) {
    int q = tid / 7, rr = tid % 7;
    const u16* qp = qhi + (bhd * LSEQ + q0 + q) * HD;
    const u16* lp = qlo + (bhd * LSEQ + q0 + q) * HD;
    const float* tp = relk + rr * HD;
    float s = 0.f;
    for (int d = 0; d < HD; ++d) s += (bf2f(qp[d]) + bf2f(lp[d])) * tp[d];
    qrel[q][rr] = s;
    arel[q][rr] = 0.f;
  }
  __syncthreads();

  // phase 1: S = Q K^T (hi/lo 3-term) -> registers sc[16] (C-layout)
  f32x4 sc[16];
  {
    const int qbase = (bhd * LSEQ + q0 + l15) * HD + quad * 8;
    bf16x8 ah0 = ld8bf(qhi + qbase);
    bf16x8 ah1 = ld8bf(qhi + qbase + 32);
    bf16x8 al0 = ld8bf(qlo + qbase);
    bf16x8 al1 = ld8bf(qlo + qbase + 32);
    const u16* bh = khi + (bhd * LSEQ + wave * 16 + l15) * HD + quad * 8;
    const u16* bl = klo + (bhd * LSEQ + wave * 16 + l15) * HD + quad * 8;
    bf16x8 kh0 = ld8bf(bh), kh1 = ld8bf(bh + 32);
    bf16x8 kl0 = ld8bf(bl), kl1 = ld8bf(bl + 32);
#pragma unroll
    for (int it = 0; it < 16; ++it) {
      bf16x8 nh0 = kh0, nh1 = kh1, nl0 = kl0, nl1 = kl1;
      if (it < 15) {
        const u16* ph = bh + (it + 1) * 4096;  // 4 tiles * 16 rows * 64
        const u16* pl = bl + (it + 1) * 4096;
        nh0 = ld8bf(ph); nh1 = ld8bf(ph + 32);
        nl0 = ld8bf(pl); nl1 = ld8bf(pl + 32);
      }
      f32x4 acc = {};
      acc = MFMA(ah0, kh0, acc);
      acc = MFMA(ah1, kh1, acc);
      acc = MFMA(ah0, kl0, acc);
      acc = MFMA(ah1, kl1, acc);
      acc = MFMA(al0, kh0, acc);
      acc = MFMA(al1, kh1, acc);
      sc[it] = acc;
      kh0 = nh0; kh1 = nh1; kl0 = nl0; kl1 = nl1;
    }
  }

  // phase 1.5: + rel scores, *8; per-row partial max
  const int colbase = wave * 16 + l15;        // col = colbase + it*64
  const int dbase = colbase - q0 - quad * 4;  // d = dbase + it*64 - r
  float mrow[4] = {-3.4e38f, -3.4e38f, -3.4e38f, -3.4e38f};
#pragma unroll
  for (int it = 0; it < 16; ++it)
#pragma unroll
    for (int r = 0; r < 4; ++r) {
      int d = dbase + it * 64 - r;
      int ri = d < -3 ? 0 : (d > 3 ? 6 : d + 3);
      float s = (sc[it][r] + qrel[quad * 4 + r][ri]) * 8.0f;
      sc[it][r] = s;
      mrow[r] = fmaxf(mrow[r], s);
    }
#pragma unroll
  for (int m = 1; m <= 8; m <<= 1)
#pragma unroll
    for (int r = 0; r < 4; ++r) mrow[r] = fmaxf(mrow[r], __shfl_xor(mrow[r], m));
  if (l15 < 4) {
    float mv = l15 == 0 ? mrow[0] : l15 == 1 ? mrow[1] : l15 == 2 ? mrow[2] : mrow[3];
    red[0][quad * 4 + l15][wave] = mv;
  }
  __syncthreads();
  float mx[4];
#pragma unroll
  for (int r = 0; r < 4; ++r) {
    int row = quad * 4 + r;
    mx[r] = fmaxf(fmaxf(red[0][row][0], red[0][row][1]),
                  fmaxf(red[0][row][2], red[0][row][3]));
  }

  // phase 2: exp + partial sums (total, d<=-3, d>=3)
  float sum[4] = {}, s0a[4] = {}, s6a[4] = {};
#pragma unroll
  for (int it = 0; it < 16; ++it)
#pragma unroll
    for (int r = 0; r < 4; ++r) {
      float e = __expf(sc[it][r] - mx[r]);
      sc[it][r] = e;
      int d = dbase + it * 64 - r;
      sum[r] += e;
      if (d <= -3) s0a[r] += e;
      if (d >= 3) s6a[r] += e;
    }
#pragma unroll
  for (int m = 1; m <= 8; m <<= 1)
#pragma unroll
    for (int r = 0; r < 4; ++r) {
      sum[r] += __shfl_xor(sum[r], m);
      s0a[r] += __shfl_xor(s0a[r], m);
      s6a[r] += __shfl_xor(s6a[r], m);
    }
  if (l15 < 4) {
    int row = quad * 4 + l15;
    float sv = l15 == 0 ? sum[0] : l15 == 1 ? sum[1] : l15 == 2 ? sum[2] : sum[3];
    float a0 = l15 == 0 ? s0a[0] : l15 == 1 ? s0a[1] : l15 == 2 ? s0a[2] : s0a[3];
    float a6 = l15 == 0 ? s6a[0] : l15 == 1 ? s6a[1] : l15 == 2 ? s6a[2] : s6a[3];
    red[1][row][wave] = sv;
    red[2][row][wave] = a0;
    red[3][row][wave] = a6;
  }
  __syncthreads();
  float rn[4];
#pragma unroll
  for (int r = 0; r < 4; ++r) {
    int row = quad * 4 + r;
    float s = red[1][row][0] + red[1][row][1] + red[1][row][2] + red[1][row][3];
    rn[r] = 1.0f / s;
    if (wave == 0 && l15 == 0) {
      float t0 = red[2][row][0] + red[2][row][1] + red[2][row][2] + red[2][row][3];
      float t6 = red[3][row][0] + red[3][row][1] + red[3][row][2] + red[3][row][3];
      arel[row][0] = t0 * rn[r];
      arel[row][6] = t6 * rn[r];
    }
  }

  // phase 2c: normalize; store attn fp32; store P bf16 to LDS; singleton buckets
  float* aob = attn_out + ((size_t)(bhd * LSEQ + q0)) * LSEQ;
#pragma unroll
  for (int it = 0; it < 16; ++it) {
    int col = colbase + it * 64;
#pragma unroll
    for (int r = 0; r < 4; ++r) {
      int row = quad * 4 + r;
      float p = sc[it][r] * rn[r];
      aob[row * LSEQ + col] = p;
      Pb[row][col] = f2bf(p);
      int d = dbase + it * 64 - r;
      if (d >= -2 && d <= 2) arel[row][d + 3] = p;
    }
  }
  __syncthreads();

  // phase 3: W1 = P @ V (wave -> 16 d-cols) + W2 = arel @ rel_v
  {
    const u16* vb = vT + (bhd * HD + wave * 16 + l15) * LSEQ;
    f32x4 acc = {};
    for (int kk = 0; kk < LSEQ; kk += 32) {
      int ak = kk + quad * 8;
      bf16x8 aP = __builtin_bit_cast(bf16x8, *(const uint4*)&Pb[l15][ak]);
      bf16x8 bV = ld8bf(vb + ak);
      acc = MFMA(aP, bV, acc);
    }
    const int col = wave * 16 + l15;  // d
#pragma unroll
    for (int r = 0; r < 4; ++r) {
      int row = quad * 4 + r;  // q within tile
      float w2 = 0.f;
#pragma unroll
      for (int t = 0; t < 7; ++t) w2 += arel[row][t] * rvt[t][col];
      wbuf[(b * LSEQ + q0 + row) * DIMM + h * HD + col] = f2bf(acc[r] + w2);
    }
  }
}

extern "C" void kernel_launch(void* const* d_in, const int* in_sizes, int n_in,
                              void* d_out, int out_size, void* d_ws, size_t ws_size,
                              hipStream_t stream) {
  const float* q_in = (const float*)d_in[0];
  const float* k_in = (const float*)d_in[1];
  const float* v_in = (const float*)d_in[2];
  const float* Wq = (const float*)d_in[3];
  const float* Wk = (const float*)d_in[4];
  const float* Wv = (const float*)d_in[5];
  const float* Wp = (const float*)d_in[6];
  const float* bias = (const float*)d_in[7];
  const float* relk = (const float*)d_in[8];
  const float* relv = (const float*)d_in[9];
  float* out = (float*)d_out;

  u16* p = (u16*)d_ws;
  u16 *AqH = p, *AqL = AqH + NXE, *AkH = AqL + NXE, *AkL = AkH + NXE,
      *Av = AkL + NXE;
  u16 *WqH = Av + NXE, *WqL = WqH + NWE, *WkH = WqL + NWE, *WkL = WkH + NWE,
      *Wvr = WkL + NWE, *Wpr = Wvr + NWE;
  u16 *qhi = Wpr + NWE, *qlo = qhi + NXE, *khi = qlo + NXE, *klo = khi + NXE,
      *vT = klo + NXE, *wbuf = vT + NXE;

  convert<<<(3 * NXE + 4 * NWE) / 1024, 256, 0, stream>>>(
      q_in, k_in, v_in, Wq, Wk, Wv, Wp, AqH, AqL, AkH, AkL, Av, WqH, WqL, WkH,
      WkL, Wvr, Wpr);
  gemm_multi<<<dim3(32, 6, 3), 256, 0, stream>>>(
      0, AqH, AqL, AkH, AkL, Av, WqH, WqL, WkH, WkL, Wvr, Wpr, wbuf, qhi, qlo,
      khi, klo, vT, out, bias);
  attn_core<<<dim3(64, NH, BATCH), 256, 0, stream>>>(
      qhi, qlo, khi, klo, vT, relk, relv, out + NXE, wbuf);
  gemm_multi<<<dim3(32, 6, 1), 256, 0, stream>>>(
      3, AqH, AqL, AkH, AkL, Av, WqH, WqL, WkH, WkL, Wvr, Wpr, wbuf, qhi, qlo,
      khi, klo, vT, out, bias);
}

// Round 7
// 434.963 us; speedup vs baseline: 1.5073x; 1.0747x over previous
//
#include <hip/hip_runtime.h>

#define DIMM 768
#define NH 12
#define HD 64
#define LSEQ 1024
#define BATCH 4
#define NXE 3145728   // 4096*768
#define NWE 589824    // 768*768

typedef __bf16 bf16x8 __attribute__((ext_vector_type(8)));
typedef float f32x4 __attribute__((ext_vector_type(4)));
typedef unsigned short u16;

static __device__ __forceinline__ u16 f2bf(float f) {
  unsigned u = __builtin_bit_cast(unsigned, f);
  u += 0x7fffu + ((u >> 16) & 1u);
  return (u16)(u >> 16);
}
static __device__ __forceinline__ float bf2f(u16 h) {
  unsigned u = ((unsigned)h) << 16;
  return __builtin_bit_cast(float, u);
}
static __device__ __forceinline__ bf16x8 ld8bf(const u16* p) {
  uint4 u = *(const uint4*)p;
  return __builtin_bit_cast(bf16x8, u);
}
#define MFMA(a, b, c) __builtin_amdgcn_mfma_f32_16x16x32_bf16(a, b, c, 0, 0, 0)
#define GLL(g, s)                                                      \
  __builtin_amdgcn_global_load_lds(                                    \
      (const __attribute__((address_space(1))) void*)(g),              \
      (__attribute__((address_space(3))) void*)(s), 16, 0, 0)

// ---------- Kernel 0: fp32 -> bf16 hi/lo conversion prepass ----------
__global__ __launch_bounds__(256) void convert(
    const float* __restrict__ q_in, const float* __restrict__ k_in,
    const float* __restrict__ v_in, const float* __restrict__ Wq,
    const float* __restrict__ Wk, const float* __restrict__ Wv,
    const float* __restrict__ Wp, u16* __restrict__ AqH, u16* __restrict__ AqL,
    u16* __restrict__ AkH, u16* __restrict__ AkL, u16* __restrict__ Av,
    u16* __restrict__ WqH, u16* __restrict__ WqL, u16* __restrict__ WkH,
    u16* __restrict__ WkL, u16* __restrict__ Wvr, u16* __restrict__ Wpr) {
  long i = ((long)blockIdx.x * 256 + threadIdx.x) * 4;
  const float* src;
  u16 *dh, *dl = nullptr;
  long off;
  if (i < NXE) { src = q_in; dh = AqH; dl = AqL; off = i; }
  else if (i < 2L * NXE) { src = k_in; dh = AkH; dl = AkL; off = i - NXE; }
  else if (i < 3L * NXE) { src = v_in; dh = Av; off = i - 2L * NXE; }
  else {
    long j = i - 3L * NXE;
    int which = (int)(j / NWE);
    off = j % NWE;
    if (which == 0) { src = Wq; dh = WqH; dl = WqL; }
    else if (which == 1) { src = Wk; dh = WkH; dl = WkL; }
    else if (which == 2) { src = Wv; dh = Wvr; }
    else { src = Wp; dh = Wpr; }
  }
  float4 v = *(const float4*)(src + off);
  ushort4 h;
  h.x = f2bf(v.x); h.y = f2bf(v.y); h.z = f2bf(v.z); h.w = f2bf(v.w);
  *(ushort4*)(dh + off) = h;
  if (dl) {
    ushort4 lo;
    lo.x = f2bf(v.x - bf2f(h.x)); lo.y = f2bf(v.y - bf2f(h.y));
    lo.z = f2bf(v.z - bf2f(h.z)); lo.w = f2bf(v.w - bf2f(h.w));
    *(ushort4*)(dl + off) = lo;
  }
}

// ---------- Kernel 1/3: 128x128-tile LDS-staged MFMA GEMM ----------
__global__ __launch_bounds__(256, 3) void gemm_multi(
    int mode0, const u16* __restrict__ AqH, const u16* __restrict__ AqL,
    const u16* __restrict__ AkH, const u16* __restrict__ AkL,
    const u16* __restrict__ Av, const u16* __restrict__ WqH,
    const u16* __restrict__ WqL, const u16* __restrict__ WkH,
    const u16* __restrict__ WkL, const u16* __restrict__ Wvr,
    const u16* __restrict__ Wpr, const u16* __restrict__ wbuf,
    u16* __restrict__ qhi, u16* __restrict__ qlo, u16* __restrict__ khi,
    u16* __restrict__ klo, u16* __restrict__ vT, float* __restrict__ outp,
    const float* __restrict__ bias) {
  __shared__ u16 sAh[128 * 32], sAl[128 * 32];
  __shared__ u16 sBh[128 * 32], sBl[128 * 32];
  const int mode = mode0 + blockIdx.z;
  const u16 *Ah, *Al = nullptr, *Bh, *Bl = nullptr;
  if (mode == 0) { Ah = AqH; Al = AqL; Bh = WqH; Bl = WqL; }
  else if (mode == 1) { Ah = AkH; Al = AkL; Bh = WkH; Bl = WkL; }
  else if (mode == 2) { Ah = Av; Bh = Wvr; }
  else { Ah = wbuf; Bh = Wpr; }
  const int t = threadIdx.x, w = t >> 6, l = t & 63;
  const int quad = l >> 4, l15 = l & 15;
  const int m0 = blockIdx.x * 128, n0 = blockIdx.y * 128;
  const int wm = (w >> 1) * 64, wn = (w & 1) * 64;
  const int srow = t >> 2, scol = (t & 3) * 8;
  const u16* gA = Ah + (m0 + srow) * DIMM + scol;
  const u16* gB = Bh + (n0 + srow) * DIMM + scol;
  u16* lA = sAh + w * 512;
  u16* lB = sBh + w * 512;
  f32x4 acc[4][4] = {};
  if (mode < 2) {
    const u16* gAl = Al + (m0 + srow) * DIMM + scol;
    const u16* gBl = Bl + (n0 + srow) * DIMM + scol;
    u16* lAl = sAl + w * 512;
    u16* lBl = sBl + w * 512;
    for (int k0 = 0; k0 < DIMM; k0 += 32) {
      GLL(gA + k0, lA);
      GLL(gA + 64 * DIMM + k0, lA + 2048);
      GLL(gAl + k0, lAl);
      GLL(gAl + 64 * DIMM + k0, lAl + 2048);
      GLL(gB + k0, lB);
      GLL(gB + 64 * DIMM + k0, lB + 2048);
      GLL(gBl + k0, lBl);
      GLL(gBl + 64 * DIMM + k0, lBl + 2048);
      __syncthreads();
      bf16x8 ah[4], bh[4], xl[4];
#pragma unroll
      for (int i = 0; i < 4; ++i)
        ah[i] = __builtin_bit_cast(
            bf16x8, *(const uint4*)(sAh + (wm + i * 16 + l15) * 32 + quad * 8));
#pragma unroll
      for (int j = 0; j < 4; ++j)
        bh[j] = __builtin_bit_cast(
            bf16x8, *(const uint4*)(sBh + (wn + j * 16 + l15) * 32 + quad * 8));
#pragma unroll
      for (int i = 0; i < 4; ++i)
#pragma unroll
        for (int j = 0; j < 4; ++j) acc[i][j] = MFMA(ah[i], bh[j], acc[i][j]);
#pragma unroll
      for (int i = 0; i < 4; ++i)
        xl[i] = __builtin_bit_cast(
            bf16x8, *(const uint4*)(sAl + (wm + i * 16 + l15) * 32 + quad * 8));
#pragma unroll
      for (int i = 0; i < 4; ++i)
#pragma unroll
        for (int j = 0; j < 4; ++j) acc[i][j] = MFMA(xl[i], bh[j], acc[i][j]);
#pragma unroll
      for (int j = 0; j < 4; ++j)
        xl[j] = __builtin_bit_cast(
            bf16x8, *(const uint4*)(sBl + (wn + j * 16 + l15) * 32 + quad * 8));
#pragma unroll
      for (int i = 0; i < 4; ++i)
#pragma unroll
        for (int j = 0; j < 4; ++j) acc[i][j] = MFMA(ah[i], xl[j], acc[i][j]);
      __syncthreads();
    }
  } else {
    for (int k0 = 0; k0 < DIMM; k0 += 32) {
      GLL(gA + k0, lA);
      GLL(gA + 64 * DIMM + k0, lA + 2048);
      GLL(gB + k0, lB);
      GLL(gB + 64 * DIMM + k0, lB + 2048);
      __syncthreads();
      bf16x8 ah[4], bh[4];
#pragma unroll
      for (int i = 0; i < 4; ++i)
        ah[i] = __builtin_bit_cast(
            bf16x8, *(const uint4*)(sAh + (wm + i * 16 + l15) * 32 + quad * 8));
#pragma unroll
      for (int j = 0; j < 4; ++j)
        bh[j] = __builtin_bit_cast(
            bf16x8, *(const uint4*)(sBh + (wn + j * 16 + l15) * 32 + quad * 8));
#pragma unroll
      for (int i = 0; i < 4; ++i)
#pragma unroll
        for (int j = 0; j < 4; ++j) acc[i][j] = MFMA(ah[i], bh[j], acc[i][j]);
      __syncthreads();
    }
  }
  u16* oh = (mode == 0) ? qhi : khi;
  u16* ol = (mode == 0) ? qlo : klo;
#pragma unroll
  for (int i = 0; i < 4; ++i)
#pragma unroll
    for (int j = 0; j < 4; ++j)
#pragma unroll
      for (int r = 0; r < 4; ++r) {
        int grow = m0 + wm + i * 16 + quad * 4 + r;  // (b,l)
        int gcol = n0 + wn + j * 16 + l15;           // (h,d)
        float c = acc[i][j][r];
        int b = grow >> 10, ll = grow & 1023, h = gcol >> 6, d = gcol & 63;
        if (mode < 2) {
          int idx = ((b * NH + h) * LSEQ + ll) * HD + d;
          u16 hi = f2bf(c);
          oh[idx] = hi;
          ol[idx] = f2bf(c - bf2f(hi));
        } else if (mode == 2) {
          vT[((b * NH + h) * HD + d) * LSEQ + ll] = f2bf(c);
        } else {
          outp[grow * DIMM + gcol] = c + bias[gcol];
        }
      }
}

// ---------- Kernel 2: attention core, LDS-staged K + register S ----------
__global__ __launch_bounds__(256, 3) void attn_core(
    const u16* __restrict__ qhi, const u16* __restrict__ qlo,
    const u16* __restrict__ khi, const u16* __restrict__ klo,
    const u16* __restrict__ vT, const float* __restrict__ relk,
    const float* __restrict__ relv, float* __restrict__ attn_out,
    u16* __restrict__ wbuf) {
  // union: phase1 K-stage (16 KB swizzled) then Pb[16][1032] bf16 (33 KB)
  __shared__ __align__(16) u16 uni[16 * 1032];
  __shared__ float qrel[16][7];
  __shared__ float arel[16][7];
  __shared__ float rvt[7][64];
  __shared__ float red[4][16][4];

  const int qt = blockIdx.x, h = blockIdx.y, b = blockIdx.z;
  const int q0 = qt * 16;
  const int tid = threadIdx.x, wave = tid >> 6, lane = tid & 63;
  const int quad = lane >> 4, l15 = lane & 15;
  const int bhd = b * NH + h;

  // phase 0: rel_v -> LDS; qrel (vectorized); zero arel
  for (int t = tid; t < 7 * HD; t += 256) rvt[t >> 6][t & 63] = relv[t];
  if (tid < 112) {
    int q = tid / 7, rr = tid % 7;
    const u16* qp = qhi + (bhd * LSEQ + q0 + q) * HD;
    const u16* lp = qlo + (bhd * LSEQ + q0 + q) * HD;
    const float* tp = relk + rr * HD;
    float s = 0.f;
#pragma unroll
    for (int d8 = 0; d8 < HD; d8 += 8) {
      uint4 uh = *(const uint4*)(qp + d8);
      uint4 ul = *(const uint4*)(lp + d8);
      float4 t0 = *(const float4*)(tp + d8);
      float4 t1 = *(const float4*)(tp + d8 + 4);
      unsigned hh[4] = {uh.x, uh.y, uh.z, uh.w};
      unsigned lv[4] = {ul.x, ul.y, ul.z, ul.w};
      float tv[8] = {t0.x, t0.y, t0.z, t0.w, t1.x, t1.y, t1.z, t1.w};
#pragma unroll
      for (int m = 0; m < 4; ++m) {
        s += (bf2f((u16)(hh[m] & 0xffff)) + bf2f((u16)(lv[m] & 0xffff))) * tv[2 * m];
        s += (bf2f((u16)(hh[m] >> 16)) + bf2f((u16)(lv[m] >> 16))) * tv[2 * m + 1];
      }
    }
    qrel[q][rr] = s;
    arel[q][rr] = 0.f;
  }

  // phase 1: S = Q K^T (hi/lo 3-term); K staged via GLL, XOR-swizzled slots
  f32x4 sc[16];
  {
    const int qbase = (bhd * LSEQ + q0 + l15) * HD + quad * 8;
    bf16x8 ah0 = ld8bf(qhi + qbase);
    bf16x8 ah1 = ld8bf(qhi + qbase + 32);
    bf16x8 al0 = ld8bf(qlo + qbase);
    bf16x8 al1 = ld8bf(qlo + qbase + 32);
    // staging: thread t supplies K[row r][cols cg*8..+8), slot index == t
    const int r = tid >> 3;                  // 0..31
    const int cg = (tid & 7) ^ (r & 7);      // XOR swizzle (conflict-free reads)
    const u16* gh = khi + (bhd * LSEQ + r) * HD + cg * 8;
    const u16* gl = klo + (bhd * LSEQ + r) * HD + cg * 8;
    u16* sb = uni + wave * 512;              // per-wave LDS base (lane*16B appended by HW)
    // read slots for this lane: row within chunk = wave*16+l15
    const int rowA = wave * 16 + l15;
    const int sw = rowA & 7;
    const int s0 = (rowA * 8 + (quad ^ sw)) * 8;        // u16 index (slot*8)
    const int s1 = (rowA * 8 + ((quad + 4) ^ sw)) * 8;
    for (int c = 0; c < 16; ++c) {
      const u16* ghc = gh + c * 64 * HD;
      const u16* glc = gl + c * 64 * HD;
      GLL(ghc, sb);                    // hi rows 0..31  -> bytes [0,4K)
      GLL(ghc + 32 * HD, sb + 2048);   // hi rows 32..63 -> [4K,8K)
      GLL(glc, sb + 4096);             // lo rows 0..31  -> [8K,12K)
      GLL(glc + 32 * HD, sb + 6144);   // lo rows 32..63 -> [12K,16K)
      __syncthreads();
      bf16x8 kh0 = ld8bf(uni + s0);
      bf16x8 kh1 = ld8bf(uni + s1);
      bf16x8 kl0 = ld8bf(uni + 4096 + s0);
      bf16x8 kl1 = ld8bf(uni + 4096 + s1);
      f32x4 e = {}, f = {};
      e = MFMA(ah0, kh0, e);
      f = MFMA(ah1, kh1, f);
      e = MFMA(ah0, kl0, e);
      f = MFMA(ah1, kl1, f);
      e = MFMA(al0, kh0, e);
      f = MFMA(al1, kh1, f);
      sc[c] = e + f;
      __syncthreads();
    }
  }

  // phase 1.5: + rel scores, *8; per-row max
  const int colbase = wave * 16 + l15;        // col = colbase + c*64
  const int dbase = colbase - q0 - quad * 4;  // d = dbase + c*64 - r
  float mrow[4] = {-3.4e38f, -3.4e38f, -3.4e38f, -3.4e38f};
#pragma unroll
  for (int c = 0; c < 16; ++c)
#pragma unroll
    for (int r = 0; r < 4; ++r) {
      int d = dbase + c * 64 - r;
      int ri = d < -3 ? 0 : (d > 3 ? 6 : d + 3);
      float s = (sc[c][r] + qrel[quad * 4 + r][ri]) * 8.0f;
      sc[c][r] = s;
      mrow[r] = fmaxf(mrow[r], s);
    }
#pragma unroll
  for (int m = 1; m <= 8; m <<= 1)
#pragma unroll
    for (int r = 0; r < 4; ++r) mrow[r] = fmaxf(mrow[r], __shfl_xor(mrow[r], m));
  if (l15 < 4) {
    float mv = l15 == 0 ? mrow[0] : l15 == 1 ? mrow[1] : l15 == 2 ? mrow[2] : mrow[3];
    red[0][quad * 4 + l15][wave] = mv;
  }
  __syncthreads();
  float mx[4];
#pragma unroll
  for (int r = 0; r < 4; ++r) {
    int row = quad * 4 + r;
    mx[r] = fmaxf(fmaxf(red[0][row][0], red[0][row][1]),
                  fmaxf(red[0][row][2], red[0][row][3]));
  }

  // phase 2: exp + partial sums (total, d<=-3, d>=3)
  float sum[4] = {}, s0a[4] = {}, s6a[4] = {};
#pragma unroll
  for (int c = 0; c < 16; ++c)
#pragma unroll
    for (int r = 0; r < 4; ++r) {
      float e = __expf(sc[c][r] - mx[r]);
      sc[c][r] = e;
      int d = dbase + c * 64 - r;
      sum[r] += e;
      if (d <= -3) s0a[r] += e;
      if (d >= 3) s6a[r] += e;
    }
#pragma unroll
  for (int m = 1; m <= 8; m <<= 1)
#pragma unroll
    for (int r = 0; r < 4; ++r) {
      sum[r] += __shfl_xor(sum[r], m);
      s0a[r] += __shfl_xor(s0a[r], m);
      s6a[r] += __shfl_xor(s6a[r], m);
    }
  if (l15 < 4) {
    int row = quad * 4 + l15;
    float sv = l15 == 0 ? sum[0] : l15 == 1 ? sum[1] : l15 == 2 ? sum[2] : sum[3];
    float a0 = l15 == 0 ? s0a[0] : l15 == 1 ? s0a[1] : l15 == 2 ? s0a[2] : s0a[3];
    float a6 = l15 == 0 ? s6a[0] : l15 == 1 ? s6a[1] : l15 == 2 ? s6a[2] : s6a[3];
    red[1][row][wave] = sv;
    red[2][row][wave] = a0;
    red[3][row][wave] = a6;
  }
  __syncthreads();
  float rn[4];
#pragma unroll
  for (int r = 0; r < 4; ++r) {
    int row = quad * 4 + r;
    float s = red[1][row][0] + red[1][row][1] + red[1][row][2] + red[1][row][3];
    rn[r] = 1.0f / s;
    if (wave == 0 && l15 == 0) {
      float t0 = red[2][row][0] + red[2][row][1] + red[2][row][2] + red[2][row][3];
      float t6 = red[3][row][0] + red[3][row][1] + red[3][row][2] + red[3][row][3];
      arel[row][0] = t0 * rn[r];
      arel[row][6] = t6 * rn[r];
    }
  }

  // phase 2c: normalize -> Pb (bf16, LDS) + singleton buckets
#pragma unroll
  for (int c = 0; c < 16; ++c) {
    int col = colbase + c * 64;
#pragma unroll
    for (int r = 0; r < 4; ++r) {
      int row = quad * 4 + r;
      float p = sc[c][r] * rn[r];
      uni[row * 1032 + col] = f2bf(p);
      int d = dbase + c * 64 - r;
      if (d >= -2 && d <= 2) arel[row][d + 3] = p;
    }
  }
  __syncthreads();

  // phase 2d: coalesced fp32 attn store from Pb (float4/thread/row)
  {
    float* aob = attn_out + ((size_t)(bhd * LSEQ + q0)) * LSEQ;
#pragma unroll
    for (int row = 0; row < 16; ++row) {
      uint2 u = *(const uint2*)&uni[row * 1032 + tid * 4];
      float4 f = {bf2f((u16)(u.x & 0xffff)), bf2f((u16)(u.x >> 16)),
                  bf2f((u16)(u.y & 0xffff)), bf2f((u16)(u.y >> 16))};
      *(float4*)(aob + row * LSEQ + tid * 4) = f;
    }
  }

  // phase 3: W1 = P @ V (wave -> 16 d-cols) + W2 = arel @ rel_v
  {
    const u16* vb = vT + (bhd * HD + wave * 16 + l15) * LSEQ;
    f32x4 acc = {};
#pragma unroll 4
    for (int kk = 0; kk < LSEQ; kk += 32) {
      int ak = kk + quad * 8;
      bf16x8 aP = __builtin_bit_cast(bf16x8, *(const uint4*)&uni[l15 * 1032 + ak]);
      bf16x8 bV = ld8bf(vb + ak);
      acc = MFMA(aP, bV, acc);
    }
    const int col = wave * 16 + l15;  // d
#pragma unroll
    for (int r = 0; r < 4; ++r) {
      int row = quad * 4 + r;  // q within tile
      float w2 = 0.f;
#pragma unroll
      for (int t = 0; t < 7; ++t) w2 += arel[row][t] * rvt[t][col];
      wbuf[(b * LSEQ + q0 + row) * DIMM + h * HD + col] = f2bf(acc[r] + w2);
    }
  }
}

extern "C" void kernel_launch(void* const* d_in, const int* in_sizes, int n_in,
                              void* d_out, int out_size, void* d_ws, size_t ws_size,
                              hipStream_t stream) {
  const float* q_in = (const float*)d_in[0];
  const float* k_in = (const float*)d_in[1];
  const float* v_in = (const float*)d_in[2];
  const float* Wq = (const float*)d_in[3];
  const float* Wk = (const float*)d_in[4];
  const float* Wv = (const float*)d_in[5];
  const float* Wp = (const float*)d_in[6];
  const float* bias = (const float*)d_in[7];
  const float* relk = (const float*)d_in[8];
  const float* relv = (const float*)d_in[9];
  float* out = (float*)d_out;

  u16* p = (u16*)d_ws;
  u16 *AqH = p, *AqL = AqH + NXE, *AkH = AqL + NXE, *AkL = AkH + NXE,
      *Av = AkL + NXE;
  u16 *WqH = Av + NXE, *WqL = WqH + NWE, *WkH = WqL + NWE, *WkL = WkH + NWE,
      *Wvr = WkL + NWE, *Wpr = Wvr + NWE;
  u16 *qhi = Wpr + NWE, *qlo = qhi + NXE, *khi = qlo + NXE, *klo = khi + NXE,
      *vT = klo + NXE, *wbuf = vT + NXE;

  convert<<<(3 * NXE + 4 * NWE) / 1024, 256, 0, stream>>>(
      q_in, k_in, v_in, Wq, Wk, Wv, Wp, AqH, AqL, AkH, AkL, Av, WqH, WqL, WkH,
      WkL, Wvr, Wpr);
  gemm_multi<<<dim3(32, 6, 3), 256, 0, stream>>>(
      0, AqH, AqL, AkH, AkL, Av, WqH, WqL, WkH, WkL, Wvr, Wpr, wbuf, qhi, qlo,
      khi, klo, vT, out, bias);
  attn_core<<<dim3(64, NH, BATCH), 256, 0, stream>>>(
      qhi, qlo, khi, klo, vT, relk, relv, out + NXE, wbuf);
  gemm_multi<<<dim3(32, 6, 1), 256, 0, stream>>>(
      3, AqH, AqL, AkH, AkL, Av, WqH, WqL, WkH, WkL, Wvr, Wpr, wbuf, qhi, qlo,
      khi, klo, vT, out, bias);
}